// Round 16
// baseline (557.003 us; speedup 1.0000x reference)
//
#include <hip/hip_runtime.h>
#include <math.h>

#define TABLE 256
#define DIM   768
#define NCH   6
#define DCH   128          // DIM / NCH
#define KTOK  12           // tokens per pass
#define CAP   64           // bucket capacity (P(cnt>64) ~ 0 for Poisson(8))

__device__ __forceinline__ float2 f2zero() { return make_float2(0.f, 0.f); }

// ---------------- kernel 1: zero counts + transpose Wrow ----------------
__global__ __launch_bounds__(256) void k_ztrans(
    const float* __restrict__ Wrow,   // (256, 768)
    float* __restrict__ WrowT,        // (768, 256)
    int* __restrict__ counts)         // (256)
{
    const int d = blockIdx.x;
    const int c = threadIdx.x;
    if (d == 0) counts[c] = 0;
    WrowT[(size_t)d * TABLE + c] = Wrow[(size_t)c * DIM + d];
}

// ---------------- kernel 2: bucket tokens by row id ----------------
__global__ __launch_bounds__(256) void k_bucket(
    const int* __restrict__ tgt, int ntok,
    int* __restrict__ counts, int* __restrict__ bucket)
{
    const int n = blockIdx.x * 256 + threadIdx.x;
    if (n >= ntok) return;
    const int r = tgt[n] >> 8;
    const int pos = atomicAdd(&counts[r], 1);
    if (pos < CAP) bucket[r * CAP + pos] = n;
}

// ---------------- register-pipeline helpers (all indices compile-time) ------
__device__ __forceinline__ void load8(float2 (&buf)[8], const float* sl, int g) {
    #pragma unroll
    for (int r = 0; r < 8; ++r)
        buf[r] = *reinterpret_cast<const float2*>(sl + (size_t)(g * 8 + r) * TABLE);
}

__device__ __forceinline__ void comp8(const float2 (&buf)[8], const float* hs_lds,
                                      float2 (&acc)[KTOK], int g) {
    #pragma unroll
    for (int h = 0; h < 2; ++h) {
        const int dq = g * 2 + h;
        float4 hv[KTOK];
        #pragma unroll
        for (int j = 0; j < KTOK; ++j)
            hv[j] = *reinterpret_cast<const float4*>(hs_lds + j * DCH + 4 * dq);
        #pragma unroll
        for (int dd = 0; dd < 4; ++dd) {
            const float2 wv = buf[h * 4 + dd];
            #pragma unroll
            for (int j = 0; j < KTOK; ++j) {
                const float hh = (dd == 0) ? hv[j].x : (dd == 1) ? hv[j].y
                               : (dd == 2) ? hv[j].z : hv[j].w;
                acc[j].x = fmaf(hh, wv.x, acc[j].x);
                acc[j].y = fmaf(hh, wv.y, acc[j].y);
            }
        }
    }
}

// ---------------- one streaming pass: 12 tokens x 128 cols x DCH d ----------
// Single wave per block. h-chunks staged in LDS (R13-proven). Slab rows flow
// through a depth-2 register pipeline: 3 named 8-row float2 buffers, 16-stage
// fully-unrolled schedule load(g+2) || compute(g) -> issue-to-use distance
// ~2 compute groups (~800cy), covering HBM latency within a single wave.
__device__ __forceinline__ void stream_pass(
    const float* __restrict__ slab,     // chunk base: (DCH, 256) floats
    const float* __restrict__ hs,       // (ntok, 768)
    const int* tk,                      // KTOK uniform token ids (clamped valid)
    int nvalid,
    int dbase,                          // chunk * DCH
    int cbase,                          // 0 or 128
    float* hs_lds,                      // LDS: KTOK * DCH floats (6 KB)
    float* __restrict__ outp,           // partial base (ntok, 256)
    int lane)
{
    // ---- stage: 2 tokens per instr, full wave, coalesced ----
    const int half = lane >> 5;
    const int q    = lane & 31;
    __syncthreads();                    // WAR guard on hs_lds (1-wave block)
    #pragma unroll
    for (int i = 0; i < KTOK / 2; ++i) {
        const int tt = (half == 0) ? tk[2 * i] : tk[2 * i + 1];
        const float4 v = *reinterpret_cast<const float4*>(
            hs + (size_t)tt * DIM + dbase + 4 * q);
        *reinterpret_cast<float4*>(hs_lds + (2 * i + half) * DCH + 4 * q) = v;
    }
    __syncthreads();                    // RAW: staging -> broadcast reads

    float2 acc[KTOK];
    #pragma unroll
    for (int j = 0; j < KTOK; ++j) acc[j] = f2zero();

    const float* sl = slab + cbase + 2 * lane;

    float2 b0[8], b1[8], b2[8];
    load8(b0, sl, 0);  load8(b1, sl, 1);
    load8(b2, sl, 2);  comp8(b0, hs_lds, acc, 0);
    load8(b0, sl, 3);  comp8(b1, hs_lds, acc, 1);
    load8(b1, sl, 4);  comp8(b2, hs_lds, acc, 2);
    load8(b2, sl, 5);  comp8(b0, hs_lds, acc, 3);
    load8(b0, sl, 6);  comp8(b1, hs_lds, acc, 4);
    load8(b1, sl, 7);  comp8(b2, hs_lds, acc, 5);
    load8(b2, sl, 8);  comp8(b0, hs_lds, acc, 6);
    load8(b0, sl, 9);  comp8(b1, hs_lds, acc, 7);
    load8(b1, sl, 10); comp8(b2, hs_lds, acc, 8);
    load8(b2, sl, 11); comp8(b0, hs_lds, acc, 9);
    load8(b0, sl, 12); comp8(b1, hs_lds, acc, 10);
    load8(b1, sl, 13); comp8(b2, hs_lds, acc, 11);
    load8(b2, sl, 14); comp8(b0, hs_lds, acc, 12);
    load8(b0, sl, 15); comp8(b1, hs_lds, acc, 13);
    comp8(b2, hs_lds, acc, 14);
    comp8(b0, hs_lds, acc, 15);

    #pragma unroll
    for (int j = 0; j < KTOK; ++j)
        if (j < nvalid)
            *reinterpret_cast<float2*>(outp + (size_t)tk[j] * TABLE + cbase + 2 * lane)
                = acc[j];
}

// ---------------- kernel 3: streaming partial GEMMs ----------------
// 64-thread blocks = 1 wave. Block id:
//   bid in [0, 3072): col head — r = bid&255, rest = bid>>8: chunk = rest>>1,
//                     cbase = (rest&1)*128
//   bid in [3072, 3072+2052): row head — b = bid-3072, tile = b%ntiles,
//                     rest = b/ntiles: chunk = rest>>1, cbase = (rest&1)*128
__global__ __launch_bounds__(64) void k_stream(
    const float* __restrict__ hs,
    const float* __restrict__ WrowT,
    const float* __restrict__ CW,
    const int* __restrict__ counts,
    const int* __restrict__ bucket,
    float* __restrict__ row_part,       // (NCH, ntok, 256)
    float* __restrict__ col_part,       // (NCH, ntok, 256)
    int ntok)
{
    __shared__ float hs_lds[KTOK * DCH];   // 6 KB

    const int bid  = blockIdx.x;
    const int lane = threadIdx.x;
    const int ncol = 256 * NCH * 2;     // 3072
    int tk[KTOK];

    if (bid < ncol) {
        const int r     = bid & 255;
        const int rest  = bid >> 8;     // 0..11
        const int chunk = rest >> 1;    // 0..5
        const int cbase = (rest & 1) * 128;
        const int cnt = min(counts[r], CAP);
        if (cnt == 0) return;
        const float* slab = CW + (size_t)r * DIM * TABLE + (size_t)chunk * DCH * TABLE;
        float* outp = col_part + (size_t)chunk * ntok * TABLE;
        for (int base = 0; base < cnt; base += KTOK) {
            #pragma unroll
            for (int j = 0; j < KTOK; ++j) {
                const int idx = (base + j < cnt) ? (base + j) : base;
                tk[j] = __builtin_amdgcn_readfirstlane(bucket[r * CAP + idx]);
            }
            stream_pass(slab, hs, tk, min(KTOK, cnt - base),
                        chunk * DCH, cbase, hs_lds, outp, lane);
        }
    } else {
        const int b      = bid - ncol;
        const int ntiles = (ntok + KTOK - 1) / KTOK;   // 171
        if (b >= ntiles * NCH * 2) return;
        const int tile   = b % ntiles;
        const int rest   = b / ntiles;  // 0..11
        const int chunk  = rest >> 1;
        const int cbase  = (rest & 1) * 128;
        const int cnt    = min(KTOK, ntok - tile * KTOK);
        #pragma unroll
        for (int j = 0; j < KTOK; ++j) {
            const int idx = (j < cnt) ? j : 0;
            tk[j] = tile * KTOK + idx;
        }
        const float* slab = WrowT + (size_t)chunk * DCH * TABLE;
        float* outp = row_part + (size_t)chunk * ntok * TABLE;
        stream_pass(slab, hs, tk, cnt, chunk * DCH, cbase, hs_lds, outp, lane);
    }
}

// ---------------- kernel 4: fused partial-sum + bias + NLL ----------------
__device__ __forceinline__ float wave_nll(float4 v, int target, int lane) {
    float m = fmaxf(fmaxf(v.x, v.y), fmaxf(v.z, v.w));
    #pragma unroll
    for (int off = 32; off > 0; off >>= 1) m = fmaxf(m, __shfl_xor(m, off));
    float e = expf(v.x - m) + expf(v.y - m) + expf(v.z - m) + expf(v.w - m);
    float lt = 0.f;
    if (lane == (target >> 2)) {
        const int j = target & 3;
        lt = (j == 0) ? v.x : (j == 1) ? v.y : (j == 2) ? v.z : v.w;
    }
    #pragma unroll
    for (int off = 32; off > 0; off >>= 1) {
        e  += __shfl_xor(e, off);
        lt += __shfl_xor(lt, off);
    }
    return m + logf(e) - lt;
}

__global__ __launch_bounds__(256) void k_nll2(
    const float* __restrict__ row_part,
    const float* __restrict__ col_part,
    const float* __restrict__ brow,
    const float* __restrict__ cbias,
    const int* __restrict__ tgt, int ntok,
    float* __restrict__ per_tok)
{
    const int n = blockIdx.x * 4 + (threadIdx.x >> 6);
    if (n >= ntok) return;
    const int lane = threadIdx.x & 63;
    const int t = tgt[n];
    const int r = t >> 8;

    float4 rl = reinterpret_cast<const float4*>(brow)[lane];
    float4 cl = reinterpret_cast<const float4*>(cbias + (size_t)r * TABLE)[lane];
    #pragma unroll
    for (int ch = 0; ch < NCH; ++ch) {
        const float4 a = reinterpret_cast<const float4*>(
            row_part + ((size_t)ch * ntok + n) * TABLE)[lane];
        const float4 b = reinterpret_cast<const float4*>(
            col_part + ((size_t)ch * ntok + n) * TABLE)[lane];
        rl.x += a.x; rl.y += a.y; rl.z += a.z; rl.w += a.w;
        cl.x += b.x; cl.y += b.y; cl.z += b.z; cl.w += b.w;
    }
    const float lr = wave_nll(rl, r, lane);
    const float lc = wave_nll(cl, t & 255, lane);
    if (lane == 0) per_tok[n] = lr + lc;
}

// ---------------- kernel 5: mean reduce ----------------
__global__ __launch_bounds__(256) void k_reduce(
    const float* __restrict__ per_tok, int ntok, float* __restrict__ out)
{
    __shared__ float red[256];
    const int c = threadIdx.x;
    float s = 0.f;
    for (int i = c; i < ntok; i += 256) s += per_tok[i];
    red[c] = s;
    __syncthreads();
    #pragma unroll
    for (int k = 128; k > 0; k >>= 1) {
        if (c < k) red[c] += red[c + k];
        __syncthreads();
    }
    if (c == 0) out[0] = red[0] / (float)ntok;
}

extern "C" void kernel_launch(void* const* d_in, const int* in_sizes, int n_in,
                              void* d_out, int out_size, void* d_ws, size_t ws_size,
                              hipStream_t stream) {
    const float* hs    = (const float*)d_in[0];
    const int*   tgt   = (const int*)d_in[1];
    const float* Wrow  = (const float*)d_in[2];
    const float* brow  = (const float*)d_in[3];
    const float* CW    = (const float*)d_in[4];
    const float* cbias = (const float*)d_in[5];
    float* out = (float*)d_out;

    const int ntok = in_sizes[1];   // 2048

    // workspace layout (bytes) — ~26.2 MB total
    char* ws = (char*)d_ws;
    int*   counts   = (int*)(ws);                                  // 1 KB
    int*   bucket   = (int*)(ws + 1024);                           // 64 KB
    float* WrowT    = (float*)(ws + 1024 + 256 * CAP * 4);         // 768 KB
    char*  p0       = (char*)WrowT + (size_t)DIM * TABLE * 4;
    float* row_part = (float*)p0;                                  // 12.6 MB
    float* col_part = row_part + (size_t)NCH * ntok * TABLE;       // 12.6 MB
    float* per_tok  = col_part + (size_t)NCH * ntok * TABLE;       // 8 KB

    const int ntiles = (ntok + KTOK - 1) / KTOK;          // 171
    const int nblk   = 256 * NCH * 2 + ntiles * NCH * 2;  // 3072 + 2052 = 5124

    k_ztrans <<<DIM, 256, 0, stream>>>(Wrow, WrowT, counts);
    k_bucket <<<(ntok + 255) / 256, 256, 0, stream>>>(tgt, ntok, counts, bucket);
    k_stream <<<nblk, 64, 0, stream>>>(hs, WrowT, CW, counts, bucket,
                                       row_part, col_part, ntok);
    k_nll2   <<<(ntok + 3) / 4, 256, 0, stream>>>(row_part, col_part, brow, cbias,
                                                  tgt, ntok, per_tok);
    k_reduce <<<1, 256, 0, stream>>>(per_tok, ntok, out);
}

// Round 18
// 72.630 us; speedup vs baseline: 7.6690x; 7.6690x over previous
//
#include <hip/hip_runtime.h>
#include <math.h>

#define TABLE 256
#define DIM   768
#define NCH   6
#define DCH   128          // DIM / NCH
#define KTOK  12           // tokens per pass
#define CAP   64           // bucket capacity (P(cnt>64) ~ 0 for Poisson(8))

__device__ __forceinline__ float2 f2zero() { return make_float2(0.f, 0.f); }

// ---------------- kernel 1: zero counts + transpose Wrow ----------------
__global__ __launch_bounds__(256) void k_ztrans(
    const float* __restrict__ Wrow,   // (256, 768)
    float* __restrict__ WrowT,        // (768, 256)
    int* __restrict__ counts)         // (256)
{
    const int d = blockIdx.x;
    const int c = threadIdx.x;
    if (d == 0) counts[c] = 0;
    WrowT[(size_t)d * TABLE + c] = Wrow[(size_t)c * DIM + d];
}

// ---------------- kernel 2: bucket tokens by row id ----------------
__global__ __launch_bounds__(256) void k_bucket(
    const int* __restrict__ tgt, int ntok,
    int* __restrict__ counts, int* __restrict__ bucket)
{
    const int n = blockIdx.x * 256 + threadIdx.x;
    if (n >= ntok) return;
    const int r = tgt[n] >> 8;
    const int pos = atomicAdd(&counts[r], 1);
    if (pos < CAP) bucket[r * CAP + pos] = n;
}

// ---------------- one streaming pass: 12 tokens x 256 cols x DCH d ----------
// 128-thread block = 2 waves sharing ONE (row, chunk) task: wave w computes
// cols [w*128, (w+1)*128). hs chunk staged into LDS ONCE per pass by both
// waves cooperatively; inner loop is R13's proven form (uniform ds broadcasts
// + float2 slab stream, #pragma unroll 2).
__device__ __forceinline__ void stream_pass(
    const float* __restrict__ slab,     // chunk base: (DCH, 256) floats
    const float* __restrict__ hs,       // (ntok, 768)
    const int* tk,                      // KTOK uniform token ids (clamped valid)
    int nvalid,
    int dbase,                          // chunk * DCH
    float* hs_lds,                      // LDS: KTOK * DCH floats (6 KB)
    float* __restrict__ outp,           // partial base (ntok, 256)
    int tid)
{
    const int lane  = tid & 63;
    const int cbase = (tid >> 6) * 128;   // wave 0 -> 0, wave 1 -> 128

    // ---- stage: 128 threads, 3 float4 each; 32-thread groups stream one
    //      token's 512B contiguously ----
    __syncthreads();                    // WAR: prior pass's reads done
    #pragma unroll
    for (int i = 0; i < KTOK / 4; ++i) {
        const int j = i * 4 + (tid >> 5);        // token index
        const int q = tid & 31;                  // quad within chunk
        const float4 v = *reinterpret_cast<const float4*>(
            hs + (size_t)tk[j] * DIM + dbase + 4 * q);
        *reinterpret_cast<float4*>(hs_lds + j * DCH + 4 * q) = v;
    }
    __syncthreads();                    // RAW: staging visible to both waves

    float2 acc[KTOK];
    #pragma unroll
    for (int j = 0; j < KTOK; ++j) acc[j] = f2zero();

    const float* sl = slab + cbase + 2 * lane;

    #pragma unroll 2
    for (int dq = 0; dq < DCH / 4; ++dq) {
        float4 hv[KTOK];                 // uniform LDS broadcasts (both waves)
        #pragma unroll
        for (int j = 0; j < KTOK; ++j)
            hv[j] = *reinterpret_cast<const float4*>(hs_lds + j * DCH + 4 * dq);
        #pragma unroll
        for (int dd = 0; dd < 4; ++dd) {
            const float2 wv = *reinterpret_cast<const float2*>(
                sl + (size_t)(dq * 4 + dd) * TABLE);
            #pragma unroll
            for (int j = 0; j < KTOK; ++j) {
                const float h = (dd == 0) ? hv[j].x : (dd == 1) ? hv[j].y
                              : (dd == 2) ? hv[j].z : hv[j].w;
                acc[j].x = fmaf(h, wv.x, acc[j].x);
                acc[j].y = fmaf(h, wv.y, acc[j].y);
            }
        }
    }

    #pragma unroll
    for (int j = 0; j < KTOK; ++j)
        if (j < nvalid)
            *reinterpret_cast<float2*>(outp + (size_t)tk[j] * TABLE + cbase + 2 * lane)
                = acc[j];
}

// ---------------- kernel 3: streaming partial GEMMs ----------------
// 128-thread blocks (2 cooperative waves). Block id:
//   bid in [0, 1536): col head — r = bid&255, chunk = bid>>8 (0..5)
//   bid in [1536, 1536+1026): row head — b = bid-1536, tile = b%171,
//                             chunk = b/171 (0..5)
__global__ __launch_bounds__(128) void k_stream(
    const float* __restrict__ hs,
    const float* __restrict__ WrowT,
    const float* __restrict__ CW,
    const int* __restrict__ counts,
    const int* __restrict__ bucket,
    float* __restrict__ row_part,       // (NCH, ntok, 256)
    float* __restrict__ col_part,       // (NCH, ntok, 256)
    int ntok)
{
    __shared__ float hs_lds[KTOK * DCH];   // 6 KB

    const int bid = blockIdx.x;
    const int tid = threadIdx.x;
    const int ncol = 256 * NCH;         // 1536
    int tk[KTOK];

    if (bid < ncol) {
        const int r     = bid & 255;
        const int chunk = bid >> 8;     // 0..5
        const int cnt = min(counts[r], CAP);
        if (cnt == 0) return;
        const float* slab = CW + (size_t)r * DIM * TABLE + (size_t)chunk * DCH * TABLE;
        float* outp = col_part + (size_t)chunk * ntok * TABLE;
        for (int base = 0; base < cnt; base += KTOK) {
            #pragma unroll
            for (int j = 0; j < KTOK; ++j) {
                const int idx = (base + j < cnt) ? (base + j) : base;
                tk[j] = __builtin_amdgcn_readfirstlane(bucket[r * CAP + idx]);
            }
            stream_pass(slab, hs, tk, min(KTOK, cnt - base),
                        chunk * DCH, hs_lds, outp, tid);
        }
    } else {
        const int b      = bid - ncol;
        const int ntiles = (ntok + KTOK - 1) / KTOK;   // 171
        if (b >= ntiles * NCH) return;
        const int tile   = b % ntiles;
        const int chunk  = b / ntiles;  // 0..5
        const int cnt    = min(KTOK, ntok - tile * KTOK);
        #pragma unroll
        for (int j = 0; j < KTOK; ++j) {
            const int idx = (j < cnt) ? j : 0;
            tk[j] = tile * KTOK + idx;
        }
        const float* slab = WrowT + (size_t)chunk * DCH * TABLE;
        float* outp = row_part + (size_t)chunk * ntok * TABLE;
        stream_pass(slab, hs, tk, cnt, chunk * DCH, hs_lds, outp, tid);
    }
}

// ---------------- kernel 4: fused partial-sum + bias + NLL ----------------
__device__ __forceinline__ float wave_nll(float4 v, int target, int lane) {
    float m = fmaxf(fmaxf(v.x, v.y), fmaxf(v.z, v.w));
    #pragma unroll
    for (int off = 32; off > 0; off >>= 1) m = fmaxf(m, __shfl_xor(m, off));
    float e = expf(v.x - m) + expf(v.y - m) + expf(v.z - m) + expf(v.w - m);
    float lt = 0.f;
    if (lane == (target >> 2)) {
        const int j = target & 3;
        lt = (j == 0) ? v.x : (j == 1) ? v.y : (j == 2) ? v.z : v.w;
    }
    #pragma unroll
    for (int off = 32; off > 0; off >>= 1) {
        e  += __shfl_xor(e, off);
        lt += __shfl_xor(lt, off);
    }
    return m + logf(e) - lt;
}

__global__ __launch_bounds__(256) void k_nll2(
    const float* __restrict__ row_part,
    const float* __restrict__ col_part,
    const float* __restrict__ brow,
    const float* __restrict__ cbias,
    const int* __restrict__ tgt, int ntok,
    float* __restrict__ per_tok)
{
    const int n = blockIdx.x * 4 + (threadIdx.x >> 6);
    if (n >= ntok) return;
    const int lane = threadIdx.x & 63;
    const int t = tgt[n];
    const int r = t >> 8;

    float4 rl = reinterpret_cast<const float4*>(brow)[lane];
    float4 cl = reinterpret_cast<const float4*>(cbias + (size_t)r * TABLE)[lane];
    #pragma unroll
    for (int ch = 0; ch < NCH; ++ch) {
        const float4 a = reinterpret_cast<const float4*>(
            row_part + ((size_t)ch * ntok + n) * TABLE)[lane];
        const float4 b = reinterpret_cast<const float4*>(
            col_part + ((size_t)ch * ntok + n) * TABLE)[lane];
        rl.x += a.x; rl.y += a.y; rl.z += a.z; rl.w += a.w;
        cl.x += b.x; cl.y += b.y; cl.z += b.z; cl.w += b.w;
    }
    const float lr = wave_nll(rl, r, lane);
    const float lc = wave_nll(cl, t & 255, lane);
    if (lane == 0) per_tok[n] = lr + lc;
}

// ---------------- kernel 5: mean reduce ----------------
__global__ __launch_bounds__(256) void k_reduce(
    const float* __restrict__ per_tok, int ntok, float* __restrict__ out)
{
    __shared__ float red[256];
    const int c = threadIdx.x;
    float s = 0.f;
    for (int i = c; i < ntok; i += 256) s += per_tok[i];
    red[c] = s;
    __syncthreads();
    #pragma unroll
    for (int k = 128; k > 0; k >>= 1) {
        if (c < k) red[c] += red[c + k];
        __syncthreads();
    }
    if (c == 0) out[0] = red[0] / (float)ntok;
}

extern "C" void kernel_launch(void* const* d_in, const int* in_sizes, int n_in,
                              void* d_out, int out_size, void* d_ws, size_t ws_size,
                              hipStream_t stream) {
    const float* hs    = (const float*)d_in[0];
    const int*   tgt   = (const int*)d_in[1];
    const float* Wrow  = (const float*)d_in[2];
    const float* brow  = (const float*)d_in[3];
    const float* CW    = (const float*)d_in[4];
    const float* cbias = (const float*)d_in[5];
    float* out = (float*)d_out;

    const int ntok = in_sizes[1];   // 2048

    // workspace layout (bytes) — ~26.2 MB total
    char* ws = (char*)d_ws;
    int*   counts   = (int*)(ws);                                  // 1 KB
    int*   bucket   = (int*)(ws + 1024);                           // 64 KB
    float* WrowT    = (float*)(ws + 1024 + 256 * CAP * 4);         // 768 KB
    char*  p0       = (char*)WrowT + (size_t)DIM * TABLE * 4;
    float* row_part = (float*)p0;                                  // 12.6 MB
    float* col_part = row_part + (size_t)NCH * ntok * TABLE;       // 12.6 MB
    float* per_tok  = col_part + (size_t)NCH * ntok * TABLE;       // 8 KB

    const int ntiles = (ntok + KTOK - 1) / KTOK;      // 171
    const int nblk   = 256 * NCH + ntiles * NCH;      // 1536 + 1026 = 2562

    k_ztrans <<<DIM, 256, 0, stream>>>(Wrow, WrowT, counts);
    k_bucket <<<(ntok + 255) / 256, 256, 0, stream>>>(tgt, ntok, counts, bucket);
    k_stream <<<nblk, 128, 0, stream>>>(hs, WrowT, CW, counts, bucket,
                                        row_part, col_part, ntok);
    k_nll2   <<<(ntok + 3) / 4, 256, 0, stream>>>(row_part, col_part, brow, cbias,
                                                  tgt, ntok, per_tok);
    k_reduce <<<1, 256, 0, stream>>>(per_tok, ntok, out);
}

// Round 19
// 72.278 us; speedup vs baseline: 7.7064x; 1.0049x over previous
//
#include <hip/hip_runtime.h>
#include <math.h>

#define TABLE 256
#define DIM   768
#define NCH   6
#define DCH   128          // d-chunk (both heads)
#define KTOK  12           // tokens per pass
#define CAP   64           // bucket capacity (P(cnt>64) ~ 0 for Poisson(8))
#define WIN   16           // slab LDS ring rows (16 KB); lookahead = WIN-4 rows

// ---------------- kernel 1: zero counts + transpose Wrow ----------------
__global__ __launch_bounds__(256) void k_ztrans(
    const float* __restrict__ Wrow,   // (256, 768)
    float* __restrict__ WrowT,        // (768, 256)
    int* __restrict__ counts)         // (256)
{
    const int d = blockIdx.x;
    const int c = threadIdx.x;
    if (d == 0) counts[c] = 0;
    WrowT[(size_t)d * TABLE + c] = Wrow[(size_t)c * DIM + d];
}

// ---------------- kernel 2: bucket tokens by row id ----------------
__global__ __launch_bounds__(256) void k_bucket(
    const int* __restrict__ tgt, int ntok,
    int* __restrict__ counts, int* __restrict__ bucket)
{
    const int n = blockIdx.x * 256 + threadIdx.x;
    if (n >= ntok) return;
    const int r = tgt[n] >> 8;
    const int pos = atomicAdd(&counts[r], 1);
    if (pos < CAP) bucket[r * CAP + pos] = n;
}

// ---- async row stage: 64 lanes x 16B = one 1KB slab row -> LDS ----
__device__ __forceinline__ void async_row(const float* g, float4* l, int lane) {
    __builtin_amdgcn_global_load_lds(
        (const __attribute__((address_space(1))) void*)(g + 4 * lane),
        (__attribute__((address_space(3))) void*)l, 16, 0, 0);
}

// ---------------- one streaming pass: 12 tokens x 256 cols x 128 d ----------
// Single wave. Slab rows flow through a WIN-row LDS ring fed by
// global_load_lds (async, no VGPR cost). Counted vmcnt waits (steady state
// vmcnt(WIN-4), never 0) keep 12 rows in flight across the whole pass.
// hs chunk staged to LDS once (R13-proven), read as uniform broadcasts.
__device__ __forceinline__ void stream_pass(
    const float* __restrict__ slab,     // chunk base: (DCH, 256) floats
    const float* __restrict__ hs,       // (ntok, 768)
    const int* tk,                      // KTOK uniform token ids (clamped valid)
    int nvalid,
    int dbase,                          // chunk * DCH
    float4 (*slab_lds)[64],             // LDS ring [WIN][64] float4 (16 KB)
    float* hs_lds,                      // LDS: KTOK * DCH floats (6 KB)
    float* __restrict__ outp,           // (ntok, 256) destination
    int lane)
{
    // ---- stage hs: 2 tokens per instr, coalesced ----
    const int half = lane >> 5;
    const int q    = lane & 31;
    #pragma unroll
    for (int i = 0; i < KTOK / 2; ++i) {
        const int tt = (half == 0) ? tk[2 * i] : tk[2 * i + 1];
        const float4 v = *reinterpret_cast<const float4*>(
            hs + (size_t)tt * DIM + dbase + 4 * q);
        *reinterpret_cast<float4*>(hs_lds + (2 * i + half) * DCH + 4 * q) = v;
    }
    // drain: hs_lds visible; vmcnt bookkeeping starts clean
    asm volatile("s_waitcnt vmcnt(0) lgkmcnt(0)" ::: "memory");

    // ---- prologue: fill the ring (WIN rows in flight) ----
    #pragma unroll
    for (int r = 0; r < WIN; ++r)
        async_row(slab + (size_t)r * TABLE, &slab_lds[r][0], lane);

    float4 acc[KTOK];
    #pragma unroll
    for (int j = 0; j < KTOK; ++j) acc[j] = make_float4(0.f, 0.f, 0.f, 0.f);

    auto compute_group = [&](int g) {
        float4 hv[KTOK];
        #pragma unroll
        for (int j = 0; j < KTOK; ++j)
            hv[j] = *reinterpret_cast<const float4*>(hs_lds + j * DCH + 4 * g);
        #pragma unroll
        for (int k = 0; k < 4; ++k) {
            const float4 wv = slab_lds[(4 * g + k) & (WIN - 1)][lane];
            #pragma unroll
            for (int j = 0; j < KTOK; ++j) {
                const float h = (k == 0) ? hv[j].x : (k == 1) ? hv[j].y
                              : (k == 2) ? hv[j].z : hv[j].w;
                acc[j].x = fmaf(h, wv.x, acc[j].x);
                acc[j].y = fmaf(h, wv.y, acc[j].y);
                acc[j].z = fmaf(h, wv.z, acc[j].z);
                acc[j].w = fmaf(h, wv.w, acc[j].w);
            }
        }
    };

    // ---- main: groups 0..28 wait vmcnt(WIN-4); issue-after-compute reuses
    //      the just-freed ring slots ((WIN+4g)&15 == (4g)&15) ----
    for (int g = 0; g < 29; ++g) {
        asm volatile("s_waitcnt vmcnt(12)" ::: "memory");
        __builtin_amdgcn_sched_barrier(0);
        compute_group(g);
        asm volatile("s_waitcnt lgkmcnt(0)" ::: "memory");  // reads retired
        if (g < 28) {
            const int ir = WIN + 4 * g;
            #pragma unroll
            for (int k = 0; k < 4; ++k)
                async_row(slab + (size_t)(ir + k) * TABLE,
                          &slab_lds[(ir + k) & (WIN - 1)][0], lane);
        }
    }
    // ---- tail: 29/30/31 with stepped waits ----
    asm volatile("s_waitcnt vmcnt(8)" ::: "memory");
    __builtin_amdgcn_sched_barrier(0);
    compute_group(29);
    asm volatile("s_waitcnt vmcnt(4)" ::: "memory");
    __builtin_amdgcn_sched_barrier(0);
    compute_group(30);
    asm volatile("s_waitcnt vmcnt(0)" ::: "memory");
    __builtin_amdgcn_sched_barrier(0);
    compute_group(31);
    asm volatile("s_waitcnt lgkmcnt(0)" ::: "memory");

    #pragma unroll
    for (int j = 0; j < KTOK; ++j)
        if (j < nvalid)
            reinterpret_cast<float4*>(outp + (size_t)tk[j] * TABLE)[lane] = acc[j];
}

// ---------------- kernel 3: streaming partial GEMMs ----------------
// 64-thread blocks = 1 wave, full 256 cols per wave. Block id:
//   bid in [0, 1536): col head — r = bid&255, chunk = bid>>8 (0..5)
//   bid in [1536, 1536+1026): row head — b = bid-1536, tile = b%171,
//                             chunk = b/171 (0..5)
__global__ __launch_bounds__(64) void k_stream(
    const float* __restrict__ hs,
    const float* __restrict__ WrowT,
    const float* __restrict__ CW,
    const int* __restrict__ counts,
    const int* __restrict__ bucket,
    float* __restrict__ row_part,       // (NCH, ntok, 256)
    float* __restrict__ col_part,       // (NCH, ntok, 256)
    int ntok)
{
    __shared__ float4 slab_lds[WIN][64];    // 16 KB ring
    __shared__ float  hs_lds[KTOK * DCH];   // 6 KB

    const int bid  = blockIdx.x;
    const int lane = threadIdx.x;
    const int ncol = 256 * NCH;         // 1536
    int tk[KTOK];

    if (bid < ncol) {
        const int r     = bid & 255;
        const int chunk = bid >> 8;     // 0..5
        const int cnt = min(counts[r], CAP);
        if (cnt == 0) return;
        const float* slab = CW + (size_t)r * DIM * TABLE + (size_t)chunk * DCH * TABLE;
        float* outp = col_part + (size_t)chunk * ntok * TABLE;
        for (int base = 0; base < cnt; base += KTOK) {
            #pragma unroll
            for (int j = 0; j < KTOK; ++j) {
                const int idx = (base + j < cnt) ? (base + j) : base;
                tk[j] = __builtin_amdgcn_readfirstlane(bucket[r * CAP + idx]);
            }
            stream_pass(slab, hs, tk, min(KTOK, cnt - base),
                        chunk * DCH, slab_lds, hs_lds, outp, lane);
        }
    } else {
        const int b      = bid - ncol;
        const int ntiles = (ntok + KTOK - 1) / KTOK;   // 171
        if (b >= ntiles * NCH) return;
        const int tile   = b % ntiles;
        const int chunk  = b / ntiles;  // 0..5
        const int cnt    = min(KTOK, ntok - tile * KTOK);
        #pragma unroll
        for (int j = 0; j < KTOK; ++j) {
            const int idx = (j < cnt) ? j : 0;
            tk[j] = tile * KTOK + idx;
        }
        const float* slab = WrowT + (size_t)chunk * DCH * TABLE;
        float* outp = row_part + (size_t)chunk * ntok * TABLE;
        stream_pass(slab, hs, tk, cnt, chunk * DCH, slab_lds, hs_lds, outp, lane);
    }
}

// ---------------- kernel 4: fused partial-sum + bias + NLL ----------------
__device__ __forceinline__ float wave_nll(float4 v, int target, int lane) {
    float m = fmaxf(fmaxf(v.x, v.y), fmaxf(v.z, v.w));
    #pragma unroll
    for (int off = 32; off > 0; off >>= 1) m = fmaxf(m, __shfl_xor(m, off));
    float e = expf(v.x - m) + expf(v.y - m) + expf(v.z - m) + expf(v.w - m);
    float lt = 0.f;
    if (lane == (target >> 2)) {
        const int j = target & 3;
        lt = (j == 0) ? v.x : (j == 1) ? v.y : (j == 2) ? v.z : v.w;
    }
    #pragma unroll
    for (int off = 32; off > 0; off >>= 1) {
        e  += __shfl_xor(e, off);
        lt += __shfl_xor(lt, off);
    }
    return m + logf(e) - lt;
}

__global__ __launch_bounds__(256) void k_nll2(
    const float* __restrict__ row_part,
    const float* __restrict__ col_part,
    const float* __restrict__ brow,
    const float* __restrict__ cbias,
    const int* __restrict__ tgt, int ntok,
    float* __restrict__ per_tok)
{
    const int n = blockIdx.x * 4 + (threadIdx.x >> 6);
    if (n >= ntok) return;
    const int lane = threadIdx.x & 63;
    const int t = tgt[n];
    const int r = t >> 8;

    float4 rl = reinterpret_cast<const float4*>(brow)[lane];
    float4 cl = reinterpret_cast<const float4*>(cbias + (size_t)r * TABLE)[lane];
    #pragma unroll
    for (int ch = 0; ch < NCH; ++ch) {
        const float4 a = reinterpret_cast<const float4*>(
            row_part + ((size_t)ch * ntok + n) * TABLE)[lane];
        const float4 b = reinterpret_cast<const float4*>(
            col_part + ((size_t)ch * ntok + n) * TABLE)[lane];
        rl.x += a.x; rl.y += a.y; rl.z += a.z; rl.w += a.w;
        cl.x += b.x; cl.y += b.y; cl.z += b.z; cl.w += b.w;
    }
    const float lr = wave_nll(rl, r, lane);
    const float lc = wave_nll(cl, t & 255, lane);
    if (lane == 0) per_tok[n] = lr + lc;
}

// ---------------- kernel 5: mean reduce ----------------
__global__ __launch_bounds__(256) void k_reduce(
    const float* __restrict__ per_tok, int ntok, float* __restrict__ out)
{
    __shared__ float red[256];
    const int c = threadIdx.x;
    float s = 0.f;
    for (int i = c; i < ntok; i += 256) s += per_tok[i];
    red[c] = s;
    __syncthreads();
    #pragma unroll
    for (int k = 128; k > 0; k >>= 1) {
        if (c < k) red[c] += red[c + k];
        __syncthreads();
    }
    if (c == 0) out[0] = red[0] / (float)ntok;
}

extern "C" void kernel_launch(void* const* d_in, const int* in_sizes, int n_in,
                              void* d_out, int out_size, void* d_ws, size_t ws_size,
                              hipStream_t stream) {
    const float* hs    = (const float*)d_in[0];
    const int*   tgt   = (const int*)d_in[1];
    const float* Wrow  = (const float*)d_in[2];
    const float* brow  = (const float*)d_in[3];
    const float* CW    = (const float*)d_in[4];
    const float* cbias = (const float*)d_in[5];
    float* out = (float*)d_out;

    const int ntok = in_sizes[1];   // 2048

    // workspace layout (bytes) — ~26.2 MB total
    char* ws = (char*)d_ws;
    int*   counts   = (int*)(ws);                                  // 1 KB
    int*   bucket   = (int*)(ws + 1024);                           // 64 KB
    float* WrowT    = (float*)(ws + 1024 + 256 * CAP * 4);         // 768 KB
    char*  p0       = (char*)WrowT + (size_t)DIM * TABLE * 4;
    float* row_part = (float*)p0;                                  // 12.6 MB
    float* col_part = row_part + (size_t)NCH * ntok * TABLE;       // 12.6 MB
    float* per_tok  = col_part + (size_t)NCH * ntok * TABLE;       // 8 KB

    const int ntiles = (ntok + KTOK - 1) / KTOK;      // 171
    const int nblk   = 256 * NCH + ntiles * NCH;      // 1536 + 1026 = 2562

    k_ztrans <<<DIM, 256, 0, stream>>>(Wrow, WrowT, counts);
    k_bucket <<<(ntok + 255) / 256, 256, 0, stream>>>(tgt, ntok, counts, bucket);
    k_stream <<<nblk, 64, 0, stream>>>(hs, WrowT, CW, counts, bucket,
                                       row_part, col_part, ntok);
    k_nll2   <<<(ntok + 3) / 4, 256, 0, stream>>>(row_part, col_part, brow, cbias,
                                                  tgt, ntok, per_tok);
    k_reduce <<<1, 256, 0, stream>>>(per_tok, ntok, out);
}